// Round 2
// baseline (499.443 us; speedup 1.0000x reference)
//
#include <hip/hip_runtime.h>

#define T_TOK 4096
#define DDIM  1024
#define IDIM  2048
#define NE    8
#define TOTROWS 8192   // T_TOK * top_k

typedef unsigned short u16;
typedef unsigned int   u32;
typedef _Float16 f16;
typedef _Float16 f16x8 __attribute__((ext_vector_type(8)));
typedef _Float16 f16x4 __attribute__((ext_vector_type(4)));
typedef float    f32x4 __attribute__((ext_vector_type(4)));

// async global->LDS, 16B per lane; LDS dest is wave-uniform base + lane*16
static __device__ __forceinline__ void gload16(const f16* g, f16* l) {
  __builtin_amdgcn_global_load_lds(
      (const __attribute__((address_space(1))) void*)g,
      (__attribute__((address_space(3))) void*)l, 16, 0, 0);
}

// ---- conf[t][e] = sigmoid(dot(x[t], Wc[e]) + bc[e]); one wave per token ----
__global__ __launch_bounds__(256) void conf_kernel(
    const float* __restrict__ x, const float* __restrict__ Wc,
    const float* __restrict__ bc, float* __restrict__ conf)
{
  int gid  = blockIdx.x * 256 + threadIdx.x;
  int t    = gid >> 6;
  int lane = threadIdx.x & 63;
  if (t >= T_TOK) return;
  const float* xr = x + (size_t)t * DDIM;
  float acc[NE];
#pragma unroll
  for (int e = 0; e < NE; e++) acc[e] = 0.f;
  for (int d = lane; d < DDIM; d += 64) {
    float xv = xr[d];
#pragma unroll
    for (int e = 0; e < NE; e++) acc[e] += xv * Wc[e * DDIM + d];
  }
#pragma unroll
  for (int off = 32; off > 0; off >>= 1) {
#pragma unroll
    for (int e = 0; e < NE; e++) acc[e] += __shfl_down(acc[e], off, 64);
  }
  if (lane == 0) {
#pragma unroll
    for (int e = 0; e < NE; e++)
      conf[t * NE + e] = 1.f / (1.f + expf(-(acc[e] + bc[e])));
  }
}

// ---- one thread per token: top-2 by conf (ties -> lower index), softmax ----
__global__ __launch_bounds__(256) void top2_kernel(
    const float* __restrict__ conf,
    int* __restrict__ counts, int* __restrict__ list, float* __restrict__ wlist)
{
  int t = blockIdx.x * 256 + threadIdx.x;
  if (t >= T_TOK) return;
  float c[NE];
#pragma unroll
  for (int e = 0; e < NE; e++) c[e] = conf[t * NE + e];
  int i0 = 0;
#pragma unroll
  for (int e = 1; e < NE; e++) if (c[e] > c[i0]) i0 = e;
  int i1 = (i0 == 0) ? 1 : 0;
#pragma unroll
  for (int e = 0; e < NE; e++) if (e != i0 && c[e] > c[i1]) i1 = e;
  float w1 = 1.f / (1.f + expf(c[i0] - c[i1]));
  float w0 = 1.f - w1;
  int s0 = atomicAdd(&counts[i0], 1);
  list[i0 * T_TOK + s0]  = t;
  wlist[i0 * T_TOK + s0] = w0;
  int s1 = atomicAdd(&counts[i1], 1);
  list[i1 * T_TOK + s1]  = t;
  wlist[i1 * T_TOK + s1] = w1;
}

// ---- prefix sum over 8 experts ---------------------------------------------
__global__ void scan_kernel(const int* __restrict__ counts, int* __restrict__ base)
{
  if (threadIdx.x == 0 && blockIdx.x == 0) {
    int s = 0;
    for (int e = 0; e < NE; e++) { base[e] = s; s += counts[e]; }
    base[NE] = s;
  }
}

// ---- x fp32 -> fp16 ---------------------------------------------------------
__global__ __launch_bounds__(256) void cvt_x_kernel(
    const float* __restrict__ x, f16* __restrict__ xh)
{
  int i = blockIdx.x * 256 + threadIdx.x;        // 1 float4 per thread
  float4 v = ((const float4*)x)[i];
  f16x4 h; h[0] = (f16)v.x; h[1] = (f16)v.y; h[2] = (f16)v.z; h[3] = (f16)v.w;
  ((f16x4*)xh)[i] = h;
}

// ---- transpose+convert: in [R][C] fp32 -> out [C][R] fp16 (per expert z) ---
__global__ __launch_bounds__(256) void tpose_kernel(
    const float* __restrict__ in, f16* __restrict__ out, int R, int C)
{
  __shared__ float t[32][33];
  const size_t mat = (size_t)R * C;
  const float* src = in  + (size_t)blockIdx.z * mat;
  f16*         dst = out + (size_t)blockIdx.z * mat;
  int c0 = blockIdx.x * 32, r0 = blockIdx.y * 32;
  int tx = threadIdx.x & 31, ty = threadIdx.x >> 5;   // 32 x 8
#pragma unroll
  for (int i = 0; i < 32; i += 8)
    t[ty + i][tx] = src[(size_t)(r0 + ty + i) * C + c0 + tx];
  __syncthreads();
#pragma unroll
  for (int i = 0; i < 32; i += 8)
    dst[(size_t)(c0 + ty + i) * R + r0 + tx] = (f16)t[tx][ty + i];
}

// ---- MFMA GEMM config -------------------------------------------------------
// 128x128 tile, BK=32, double-buffered LDS, 4 waves (2x2), wave tile 64x64,
// mfma_f32_16x16x32_f16. LDS rows = 32 f16 = 64B = 4 slots of 16B.
// Swizzle: phys_slot = logical_slot ^ ((row>>1)&3); since all fragment rows
// differ from (lane&15) by multiples of 16, phys = kg ^ (((l&15)>>1)&3) for
// every fragment. global_load_lds writes linearly, so the inverse swizzle is
// applied on the per-lane GLOBAL source slot: sl = (l&3) ^ ((l>>3)&3).
constexpr int BK = 32;

// ---- GEMM1: h[slot][n] = silu(x@Wg)*(x@Wu)*w, fp16 out ---------------------
__global__ __launch_bounds__(256, 2) void gemm1_kernel(
    const f16* __restrict__ xh, const f16* __restrict__ WgT, const f16* __restrict__ WuT,
    const int* __restrict__ counts, const int* __restrict__ base,
    const int* __restrict__ list, const float* __restrict__ wlist,
    f16* __restrict__ hbuf)
{
  const int e   = blockIdx.z;
  const int cnt = counts[e];
  const int p0  = blockIdx.y * 128;
  if (p0 >= cnt) return;
  const int n0  = blockIdx.x * 128;

  __shared__ __align__(16) f16 As [2][128 * BK];
  __shared__ __align__(16) f16 Bgs[2][128 * BK];
  __shared__ __align__(16) f16 Bus[2][128 * BK];
  __shared__ int   tokS[128];
  __shared__ float wS[128];

  const int tid = threadIdx.x;
  if (tid < 128) {
    int p = p0 + tid;
    tokS[tid] = (p < cnt) ? list[e * T_TOK + p] : 0;
    wS[tid]   = (p < cnt) ? wlist[e * T_TOK + p] : 0.f;
  }
  __syncthreads();

  const int l   = tid & 63;
  const int w   = tid >> 6;
  const int wr  = w >> 1, wc = w & 1;
  const int r15 = l & 15;
  const int kg  = l >> 4;

  // staging source pointers (wave w stages row-groups j = 2w, 2w+1 of each tile)
  const int rl4 = l >> 2;                       // row within 16-row group
  const int sl  = (l & 3) ^ ((l >> 3) & 3);     // inverse-swizzled source slot
  const f16* WgE = WgT + ((size_t)e << 21);
  const f16* WuE = WuT + ((size_t)e << 21);
  const f16* srcA[2]; const f16* srcG[2]; const f16* srcU[2];
#pragma unroll
  for (int ii = 0; ii < 2; ii++) {
    int j = 2 * w + ii;
    int row = j * 16 + rl4;
    srcA[ii] = xh  + (size_t)tokS[row] * DDIM + sl * 8;
    srcG[ii] = WgE + (size_t)(n0 + row) * DDIM + sl * 8;
    srcU[ii] = WuE + (size_t)(n0 + row) * DDIM + sl * 8;
  }

  // fragment-read LDS offsets (f16 units)
  const int phys = kg ^ ((r15 >> 1) & 3);
  const int aoff = (wr * 64 + r15) * BK + phys * 8;   // + mi*512
  const int boff = (wc * 64 + r15) * BK + phys * 8;   // + ni*512

  f32x4 accg[4][4], accu[4][4];
#pragma unroll
  for (int a = 0; a < 4; a++)
#pragma unroll
    for (int bq = 0; bq < 4; bq++)
#pragma unroll
      for (int r = 0; r < 4; r++) { accg[a][bq][r] = 0.f; accu[a][bq][r] = 0.f; }

#define STAGE1(KT, B) do {                                   \
    int koff = (KT) * BK;                                    \
    _Pragma("unroll")                                        \
    for (int ii = 0; ii < 2; ii++) {                         \
      int j = 2 * w + ii;                                    \
      gload16(srcA[ii] + koff, &As [B][j * 512]);            \
      gload16(srcG[ii] + koff, &Bgs[B][j * 512]);            \
      gload16(srcU[ii] + koff, &Bus[B][j * 512]);            \
    }                                                        \
  } while (0)

  STAGE1(0, 0);
  constexpr int NT = DDIM / BK;   // 32
  for (int kt = 0; kt < NT; kt++) {
    const int b = kt & 1;
    __syncthreads();                 // tile kt staged; prev ds_reads done
    if (kt + 1 < NT) STAGE1(kt + 1, b ^ 1);   // latency hidden under compute

    f16x8 av[4], bgv[4], buv[4];
#pragma unroll
    for (int mi = 0; mi < 4; mi++) av[mi] = *(const f16x8*)&As[b][aoff + mi * 512];
#pragma unroll
    for (int ni = 0; ni < 4; ni++) {
      bgv[ni] = *(const f16x8*)&Bgs[b][boff + ni * 512];
      buv[ni] = *(const f16x8*)&Bus[b][boff + ni * 512];
    }
#pragma unroll
    for (int mi = 0; mi < 4; mi++)
#pragma unroll
      for (int ni = 0; ni < 4; ni++) {
        accg[mi][ni] = __builtin_amdgcn_mfma_f32_16x16x32_f16(av[mi], bgv[ni], accg[mi][ni], 0, 0, 0);
        accu[mi][ni] = __builtin_amdgcn_mfma_f32_16x16x32_f16(av[mi], buv[ni], accu[mi][ni], 0, 0, 0);
      }
  }
#undef STAGE1

  // epilogue: 16x16 C/D layout: col=lane&15, row=(lane>>4)*4 + reg
  const int rowbase = base[e] + p0;
#pragma unroll
  for (int mi = 0; mi < 4; mi++)
#pragma unroll
    for (int ni = 0; ni < 4; ni++) {
      int col = n0 + wc * 64 + ni * 16 + r15;
#pragma unroll
      for (int r = 0; r < 4; r++) {
        int p = wr * 64 + mi * 16 + kg * 4 + r;
        if (p0 + p < cnt) {
          float g = accg[mi][ni][r], u = accu[mi][ni][r];
          hbuf[(size_t)(rowbase + p) * IDIM + col] = (f16)(g / (1.f + expf(-g)) * u * wS[p]);
        }
      }
    }
}

// ---- GEMM2: out[tok,:] += h_row @ Wd[e]  (fp32 atomic combine) -------------
__global__ __launch_bounds__(256, 2) void gemm2_kernel(
    const f16* __restrict__ hbuf, const f16* __restrict__ WdT,
    const int* __restrict__ counts, const int* __restrict__ base,
    const int* __restrict__ list, float* __restrict__ out)
{
  const int e   = blockIdx.z;
  const int cnt = counts[e];
  const int p0  = blockIdx.y * 128;
  if (p0 >= cnt) return;
  const int n0  = blockIdx.x * 128;

  __shared__ __align__(16) f16 Hs [2][128 * BK];
  __shared__ __align__(16) f16 Bds[2][128 * BK];
  __shared__ int tokS[128];

  const int tid = threadIdx.x;
  if (tid < 128) {
    int p = p0 + tid;
    tokS[tid] = (p < cnt) ? list[e * T_TOK + p] : 0;
  }
  __syncthreads();

  const int l   = tid & 63;
  const int w   = tid >> 6;
  const int wr  = w >> 1, wc = w & 1;
  const int r15 = l & 15;
  const int kg  = l >> 4;

  const int rl4 = l >> 2;
  const int sl  = (l & 3) ^ ((l >> 3) & 3);
  const int rowbase = base[e] + p0;
  const f16* WdE = WdT + ((size_t)e << 21);
  const f16* srcH[2]; const f16* srcD[2];
#pragma unroll
  for (int ii = 0; ii < 2; ii++) {
    int j = 2 * w + ii;
    int row = j * 16 + rl4;
    int hr = rowbase + row; if (hr > TOTROWS - 1) hr = TOTROWS - 1;  // pad clamp
    srcH[ii] = hbuf + (size_t)hr * IDIM + sl * 8;
    srcD[ii] = WdE  + (size_t)(n0 + row) * IDIM + sl * 8;
  }

  const int phys = kg ^ ((r15 >> 1) & 3);
  const int aoff = (wr * 64 + r15) * BK + phys * 8;
  const int boff = (wc * 64 + r15) * BK + phys * 8;

  f32x4 acc[4][4];
#pragma unroll
  for (int a = 0; a < 4; a++)
#pragma unroll
    for (int bq = 0; bq < 4; bq++)
#pragma unroll
      for (int r = 0; r < 4; r++) acc[a][bq][r] = 0.f;

#define STAGE2(KT, B) do {                                   \
    int koff = (KT) * BK;                                    \
    _Pragma("unroll")                                        \
    for (int ii = 0; ii < 2; ii++) {                         \
      int j = 2 * w + ii;                                    \
      gload16(srcH[ii] + koff, &Hs [B][j * 512]);            \
      gload16(srcD[ii] + koff, &Bds[B][j * 512]);            \
    }                                                        \
  } while (0)

  STAGE2(0, 0);
  constexpr int NT = IDIM / BK;   // 64
  for (int kt = 0; kt < NT; kt++) {
    const int b = kt & 1;
    __syncthreads();
    if (kt + 1 < NT) STAGE2(kt + 1, b ^ 1);

    f16x8 av[4], bdv[4];
#pragma unroll
    for (int mi = 0; mi < 4; mi++) av[mi] = *(const f16x8*)&Hs[b][aoff + mi * 512];
#pragma unroll
    for (int ni = 0; ni < 4; ni++) bdv[ni] = *(const f16x8*)&Bds[b][boff + ni * 512];
#pragma unroll
    for (int mi = 0; mi < 4; mi++)
#pragma unroll
      for (int ni = 0; ni < 4; ni++)
        acc[mi][ni] = __builtin_amdgcn_mfma_f32_16x16x32_f16(av[mi], bdv[ni], acc[mi][ni], 0, 0, 0);
  }
#undef STAGE2

#pragma unroll
  for (int mi = 0; mi < 4; mi++)
#pragma unroll
    for (int ni = 0; ni < 4; ni++) {
      int col = n0 + wc * 64 + ni * 16 + r15;
#pragma unroll
      for (int r = 0; r < 4; r++) {
        int p = wr * 64 + mi * 16 + kg * 4 + r;
        if (p0 + p < cnt)
          atomicAdd(&out[(size_t)tokS[p] * DDIM + col], acc[mi][ni][r]);
      }
    }
}

// ---- launch -----------------------------------------------------------------
extern "C" void kernel_launch(void* const* d_in, const int* in_sizes, int n_in,
                              void* d_out, int out_size, void* d_ws, size_t ws_size,
                              hipStream_t stream)
{
  const float* x  = (const float*)d_in[0];
  const float* Wc = (const float*)d_in[1];
  const float* bc = (const float*)d_in[2];
  const float* Wg = (const float*)d_in[3];
  const float* Wu = (const float*)d_in[4];
  const float* Wd = (const float*)d_in[5];
  float* out = (float*)d_out;

  char* ws = (char*)d_ws;
  int*   counts = (int*)(ws + 0);              // 64 B
  int*   base   = (int*)(ws + 256);            // 36 B
  float* conf   = (float*)(ws + 1024);         // 128 KiB -> 132096
  int*   list   = (int*)(ws + 132096);         // 128 KiB -> 263168
  float* wlist  = (float*)(ws + 263168);       // 128 KiB -> 394240
  f16*   xh     = (f16*)(ws + 394240);         // 8 MiB   -> 8782848
  f16*   hbuf   = (f16*)(ws + 8782848);        // 32 MiB  -> 42337280
  f16*   W1     = (f16*)(ws + 42337280);       // 32 MiB  -> 75891712  (WgT, then WdT)
  f16*   W2     = (f16*)(ws + 75891712);       // 32 MiB  -> 109446144 (WuT)

  hipMemsetAsync(counts, 0, 64, stream);
  hipMemsetAsync(out, 0, (size_t)out_size * sizeof(float), stream);

  conf_kernel<<<T_TOK / 4, 256, 0, stream>>>(x, Wc, bc, conf);
  top2_kernel<<<T_TOK / 256, 256, 0, stream>>>(conf, counts, list, wlist);
  scan_kernel<<<1, 64, 0, stream>>>(counts, base);

  cvt_x_kernel<<<T_TOK * DDIM / 1024, 256, 0, stream>>>(x, xh);
  dim3 gt1(IDIM / 32, DDIM / 32, NE);
  tpose_kernel<<<gt1, 256, 0, stream>>>(Wg, W1, DDIM, IDIM);  // WgT [I][D]
  tpose_kernel<<<gt1, 256, 0, stream>>>(Wu, W2, DDIM, IDIM);  // WuT [I][D]

  dim3 g1(IDIM / 128, T_TOK / 128, NE);
  gemm1_kernel<<<g1, 256, 0, stream>>>(xh, W1, W2, counts, base, list, wlist, hbuf);

  dim3 gt2(DDIM / 32, IDIM / 32, NE);
  tpose_kernel<<<gt2, 256, 0, stream>>>(Wd, W1, IDIM, DDIM);  // WdT [D][I], reuse W1

  dim3 g2(DDIM / 128, T_TOK / 128, NE);
  gemm2_kernel<<<g2, 256, 0, stream>>>(hbuf, W1, counts, base, list, out);
}

// Round 3
// 468.479 us; speedup vs baseline: 1.0661x; 1.0661x over previous
//
#include <hip/hip_runtime.h>

#define T_TOK 4096
#define DDIM  1024
#define IDIM  2048
#define NE    8
#define TOTROWS 8192   // T_TOK * top_k

typedef unsigned short u16;
typedef unsigned int   u32;
typedef _Float16 f16;
typedef _Float16 f16x8 __attribute__((ext_vector_type(8)));
typedef _Float16 f16x4 __attribute__((ext_vector_type(4)));
typedef float    f32x4 __attribute__((ext_vector_type(4)));

// counted vmcnt wait: lets prefetched global_load_lds stay in flight (T4)
#define WAITV(N) asm volatile("s_waitcnt vmcnt(" #N ")" ::: "memory")

// async global->LDS, 16B per lane; LDS dest is wave-uniform base + lane*16
static __device__ __forceinline__ void gload16(const f16* g, f16* l) {
  __builtin_amdgcn_global_load_lds(
      (const __attribute__((address_space(1))) void*)g,
      (__attribute__((address_space(3))) void*)l, 16, 0, 0);
}

// ---- conf[t][e] = sigmoid(dot(x[t], Wc[e]) + bc[e]); one wave per token ----
__global__ __launch_bounds__(256) void conf_kernel(
    const float* __restrict__ x, const float* __restrict__ Wc,
    const float* __restrict__ bc, float* __restrict__ conf)
{
  int gid  = blockIdx.x * 256 + threadIdx.x;
  int t    = gid >> 6;
  int lane = threadIdx.x & 63;
  if (t >= T_TOK) return;
  const float* xr = x + (size_t)t * DDIM;
  float acc[NE];
#pragma unroll
  for (int e = 0; e < NE; e++) acc[e] = 0.f;
  for (int d = lane; d < DDIM; d += 64) {
    float xv = xr[d];
#pragma unroll
    for (int e = 0; e < NE; e++) acc[e] += xv * Wc[e * DDIM + d];
  }
#pragma unroll
  for (int off = 32; off > 0; off >>= 1) {
#pragma unroll
    for (int e = 0; e < NE; e++) acc[e] += __shfl_down(acc[e], off, 64);
  }
  if (lane == 0) {
#pragma unroll
    for (int e = 0; e < NE; e++)
      conf[t * NE + e] = 1.f / (1.f + expf(-(acc[e] + bc[e])));
  }
}

// ---- one thread per token: top-2 by conf (ties -> lower index), softmax ----
__global__ __launch_bounds__(256) void top2_kernel(
    const float* __restrict__ conf,
    int* __restrict__ counts, int* __restrict__ list, float* __restrict__ wlist)
{
  int t = blockIdx.x * 256 + threadIdx.x;
  if (t >= T_TOK) return;
  float c[NE];
#pragma unroll
  for (int e = 0; e < NE; e++) c[e] = conf[t * NE + e];
  int i0 = 0;
#pragma unroll
  for (int e = 1; e < NE; e++) if (c[e] > c[i0]) i0 = e;
  int i1 = (i0 == 0) ? 1 : 0;
#pragma unroll
  for (int e = 0; e < NE; e++) if (e != i0 && c[e] > c[i1]) i1 = e;
  float w1 = 1.f / (1.f + expf(c[i0] - c[i1]));
  float w0 = 1.f - w1;
  int s0 = atomicAdd(&counts[i0], 1);
  list[i0 * T_TOK + s0]  = t;
  wlist[i0 * T_TOK + s0] = w0;
  int s1 = atomicAdd(&counts[i1], 1);
  list[i1 * T_TOK + s1]  = t;
  wlist[i1 * T_TOK + s1] = w1;
}

// ---- prefix sum over 8 experts ---------------------------------------------
__global__ void scan_kernel(const int* __restrict__ counts, int* __restrict__ base)
{
  if (threadIdx.x == 0 && blockIdx.x == 0) {
    int s = 0;
    for (int e = 0; e < NE; e++) { base[e] = s; s += counts[e]; }
    base[NE] = s;
  }
}

// ---- x fp32 -> fp16 ---------------------------------------------------------
__global__ __launch_bounds__(256) void cvt_x_kernel(
    const float* __restrict__ x, f16* __restrict__ xh)
{
  int i = blockIdx.x * 256 + threadIdx.x;        // 1 float4 per thread
  float4 v = ((const float4*)x)[i];
  f16x4 h; h[0] = (f16)v.x; h[1] = (f16)v.y; h[2] = (f16)v.z; h[3] = (f16)v.w;
  ((f16x4*)xh)[i] = h;
}

// ---- transpose+convert: in [R][C] fp32 -> out [C][R] fp16 (per expert z) ---
__global__ __launch_bounds__(256) void tpose_kernel(
    const float* __restrict__ in, f16* __restrict__ out, int R, int C)
{
  __shared__ float t[32][33];
  const size_t mat = (size_t)R * C;
  const float* src = in  + (size_t)blockIdx.z * mat;
  f16*         dst = out + (size_t)blockIdx.z * mat;
  int c0 = blockIdx.x * 32, r0 = blockIdx.y * 32;
  int tx = threadIdx.x & 31, ty = threadIdx.x >> 5;   // 32 x 8
#pragma unroll
  for (int i = 0; i < 32; i += 8)
    t[ty + i][tx] = src[(size_t)(r0 + ty + i) * C + c0 + tx];
  __syncthreads();
#pragma unroll
  for (int i = 0; i < 32; i += 8)
    dst[(size_t)(c0 + ty + i) * R + r0 + tx] = (f16)t[tx][ty + i];
}

// ---- MFMA GEMM config -------------------------------------------------------
// 128x128 tile, BK=32, TRIPLE-buffered LDS, depth-2 counted-vmcnt pipeline,
// 4 waves (2x2), wave tile 64x64, mfma_f32_16x16x32_f16.
// LDS rows = 32 f16 = 64B = 4 slots of 16B. Swizzle (verified: 0 conflicts):
// phys_slot = kg ^ ((r15>>1)&3); inverse applied on per-lane GLOBAL source
// slot sl = (l&3) ^ ((l>>3)&3) since global_load_lds writes linearly.
constexpr int BK = 32;

// ---- GEMM1: h[slot][n] = silu(x@Wg)*(x@Wu)*w, fp16 out ---------------------
__global__ __launch_bounds__(256, 2) void gemm1_kernel(
    const f16* __restrict__ xh, const f16* __restrict__ WgT, const f16* __restrict__ WuT,
    const int* __restrict__ counts, const int* __restrict__ base,
    const int* __restrict__ list, const float* __restrict__ wlist,
    f16* __restrict__ hbuf)
{
  const int e   = blockIdx.z;
  const int cnt = counts[e];
  const int p0  = blockIdx.y * 128;
  if (p0 >= cnt) return;
  const int n0  = blockIdx.x * 128;

  __shared__ __align__(16) f16 As [3][128 * BK];
  __shared__ __align__(16) f16 Bgs[3][128 * BK];
  __shared__ __align__(16) f16 Bus[3][128 * BK];
  __shared__ int   tokS[128];
  __shared__ float wS[128];

  const int tid = threadIdx.x;
  if (tid < 128) {
    int p = p0 + tid;
    tokS[tid] = (p < cnt) ? list[e * T_TOK + p] : 0;
    wS[tid]   = (p < cnt) ? wlist[e * T_TOK + p] : 0.f;
  }
  __syncthreads();   // also drains tokS loads -> clean vmcnt accounting

  const int l   = tid & 63;
  const int w   = tid >> 6;
  const int wr  = w >> 1, wc = w & 1;
  const int r15 = l & 15;
  const int kg  = l >> 4;

  // staging source pointers (wave w stages row-groups j = 2w, 2w+1 of each tile)
  const int rl4 = l >> 2;                       // row within 16-row group
  const int sl  = (l & 3) ^ ((l >> 3) & 3);     // inverse-swizzled source slot
  const f16* WgE = WgT + ((size_t)e << 21);
  const f16* WuE = WuT + ((size_t)e << 21);
  const f16* srcA[2]; const f16* srcG[2]; const f16* srcU[2];
#pragma unroll
  for (int ii = 0; ii < 2; ii++) {
    int j = 2 * w + ii;
    int row = j * 16 + rl4;
    srcA[ii] = xh  + (size_t)tokS[row] * DDIM + sl * 8;
    srcG[ii] = WgE + (size_t)(n0 + row) * DDIM + sl * 8;
    srcU[ii] = WuE + (size_t)(n0 + row) * DDIM + sl * 8;
  }

  // fragment-read LDS offsets (f16 units)
  const int phys = kg ^ ((r15 >> 1) & 3);
  const int aoff = (wr * 64 + r15) * BK + phys * 8;   // + mi*512
  const int boff = (wc * 64 + r15) * BK + phys * 8;   // + ni*512

  f32x4 accg[4][4], accu[4][4];
#pragma unroll
  for (int a = 0; a < 4; a++)
#pragma unroll
    for (int bq = 0; bq < 4; bq++)
#pragma unroll
      for (int r = 0; r < 4; r++) { accg[a][bq][r] = 0.f; accu[a][bq][r] = 0.f; }

#define STAGE1(KT, B) do {                                   \
    int koff = (KT) * BK;                                    \
    _Pragma("unroll")                                        \
    for (int ii = 0; ii < 2; ii++) {                         \
      int j = 2 * w + ii;                                    \
      gload16(srcA[ii] + koff, &As [B][j * 512]);            \
      gload16(srcG[ii] + koff, &Bgs[B][j * 512]);            \
      gload16(srcU[ii] + koff, &Bus[B][j * 512]);            \
    }                                                        \
  } while (0)

  STAGE1(0, 0);          // 6 loads in flight
  STAGE1(1, 1);          // 12 in flight
  constexpr int NT = DDIM / BK;   // 32
  int cb = 0;            // compute buffer = kt % 3
  for (int kt = 0; kt < NT; kt++) {
    // wait for tile kt only; tile kt+1's 6 loads stay in flight (never drain 0)
    if (kt + 1 < NT) { WAITV(6); } else { WAITV(0); }
    __builtin_amdgcn_s_barrier();
    if (kt + 2 < NT) {
      int sb = (cb == 0) ? 2 : cb - 1;    // (kt+2)%3 — buffer freed by this barrier
      STAGE1(kt + 2, sb);                 // back to 12 in flight
    }

    f16x8 av[4], bgv[4], buv[4];
#pragma unroll
    for (int mi = 0; mi < 4; mi++) av[mi] = *(const f16x8*)&As[cb][aoff + mi * 512];
#pragma unroll
    for (int ni = 0; ni < 4; ni++) {
      bgv[ni] = *(const f16x8*)&Bgs[cb][boff + ni * 512];
      buv[ni] = *(const f16x8*)&Bus[cb][boff + ni * 512];
    }
    __builtin_amdgcn_s_setprio(1);
#pragma unroll
    for (int mi = 0; mi < 4; mi++)
#pragma unroll
      for (int ni = 0; ni < 4; ni++) {
        accg[mi][ni] = __builtin_amdgcn_mfma_f32_16x16x32_f16(av[mi], bgv[ni], accg[mi][ni], 0, 0, 0);
        accu[mi][ni] = __builtin_amdgcn_mfma_f32_16x16x32_f16(av[mi], buv[ni], accu[mi][ni], 0, 0, 0);
      }
    __builtin_amdgcn_s_setprio(0);
    cb = (cb == 2) ? 0 : cb + 1;
  }
#undef STAGE1

  // epilogue: 16x16 C/D layout: col=lane&15, row=(lane>>4)*4 + reg
  const int rowbase = base[e] + p0;
#pragma unroll
  for (int mi = 0; mi < 4; mi++)
#pragma unroll
    for (int ni = 0; ni < 4; ni++) {
      int col = n0 + wc * 64 + ni * 16 + r15;
#pragma unroll
      for (int r = 0; r < 4; r++) {
        int p = wr * 64 + mi * 16 + kg * 4 + r;
        if (p0 + p < cnt) {
          float g = accg[mi][ni][r], u = accu[mi][ni][r];
          hbuf[(size_t)(rowbase + p) * IDIM + col] = (f16)(g / (1.f + expf(-g)) * u * wS[p]);
        }
      }
    }
}

// ---- GEMM2: out[tok,:] += h_row @ Wd[e]  (fp32 atomic combine) -------------
__global__ __launch_bounds__(256, 3) void gemm2_kernel(
    const f16* __restrict__ hbuf, const f16* __restrict__ WdT,
    const int* __restrict__ counts, const int* __restrict__ base,
    const int* __restrict__ list, float* __restrict__ out)
{
  const int e   = blockIdx.z;
  const int cnt = counts[e];
  const int p0  = blockIdx.y * 128;
  if (p0 >= cnt) return;
  const int n0  = blockIdx.x * 128;

  __shared__ __align__(16) f16 Hs [3][128 * BK];
  __shared__ __align__(16) f16 Bds[3][128 * BK];
  __shared__ int tokS[128];

  const int tid = threadIdx.x;
  if (tid < 128) {
    int p = p0 + tid;
    tokS[tid] = (p < cnt) ? list[e * T_TOK + p] : 0;
  }
  __syncthreads();

  const int l   = tid & 63;
  const int w   = tid >> 6;
  const int wr  = w >> 1, wc = w & 1;
  const int r15 = l & 15;
  const int kg  = l >> 4;

  const int rl4 = l >> 2;
  const int sl  = (l & 3) ^ ((l >> 3) & 3);
  const int rowbase = base[e] + p0;
  const f16* WdE = WdT + ((size_t)e << 21);
  const f16* srcH[2]; const f16* srcD[2];
#pragma unroll
  for (int ii = 0; ii < 2; ii++) {
    int j = 2 * w + ii;
    int row = j * 16 + rl4;
    int hr = rowbase + row; if (hr > TOTROWS - 1) hr = TOTROWS - 1;  // pad clamp
    srcH[ii] = hbuf + (size_t)hr * IDIM + sl * 8;
    srcD[ii] = WdE  + (size_t)(n0 + row) * IDIM + sl * 8;
  }

  const int phys = kg ^ ((r15 >> 1) & 3);
  const int aoff = (wr * 64 + r15) * BK + phys * 8;
  const int boff = (wc * 64 + r15) * BK + phys * 8;

  f32x4 acc[4][4];
#pragma unroll
  for (int a = 0; a < 4; a++)
#pragma unroll
    for (int bq = 0; bq < 4; bq++)
#pragma unroll
      for (int r = 0; r < 4; r++) acc[a][bq][r] = 0.f;

#define STAGE2(KT, B) do {                                   \
    int koff = (KT) * BK;                                    \
    _Pragma("unroll")                                        \
    for (int ii = 0; ii < 2; ii++) {                         \
      int j = 2 * w + ii;                                    \
      gload16(srcH[ii] + koff, &Hs [B][j * 512]);            \
      gload16(srcD[ii] + koff, &Bds[B][j * 512]);            \
    }                                                        \
  } while (0)

  STAGE2(0, 0);          // 4 in flight
  STAGE2(1, 1);          // 8 in flight
  constexpr int NT = IDIM / BK;   // 64
  int cb = 0;
  for (int kt = 0; kt < NT; kt++) {
    if (kt + 1 < NT) { WAITV(4); } else { WAITV(0); }
    __builtin_amdgcn_s_barrier();
    if (kt + 2 < NT) {
      int sb = (cb == 0) ? 2 : cb - 1;
      STAGE2(kt + 2, sb);
    }

    f16x8 av[4], bdv[4];
#pragma unroll
    for (int mi = 0; mi < 4; mi++) av[mi] = *(const f16x8*)&Hs[cb][aoff + mi * 512];
#pragma unroll
    for (int ni = 0; ni < 4; ni++) bdv[ni] = *(const f16x8*)&Bds[cb][boff + ni * 512];
    __builtin_amdgcn_s_setprio(1);
#pragma unroll
    for (int mi = 0; mi < 4; mi++)
#pragma unroll
      for (int ni = 0; ni < 4; ni++)
        acc[mi][ni] = __builtin_amdgcn_mfma_f32_16x16x32_f16(av[mi], bdv[ni], acc[mi][ni], 0, 0, 0);
    __builtin_amdgcn_s_setprio(0);
    cb = (cb == 2) ? 0 : cb + 1;
  }
#undef STAGE2

#pragma unroll
  for (int mi = 0; mi < 4; mi++)
#pragma unroll
    for (int ni = 0; ni < 4; ni++) {
      int col = n0 + wc * 64 + ni * 16 + r15;
#pragma unroll
      for (int r = 0; r < 4; r++) {
        int p = wr * 64 + mi * 16 + kg * 4 + r;
        if (p0 + p < cnt)
          atomicAdd(&out[(size_t)tokS[p] * DDIM + col], acc[mi][ni][r]);
      }
    }
}

// ---- launch -----------------------------------------------------------------
extern "C" void kernel_launch(void* const* d_in, const int* in_sizes, int n_in,
                              void* d_out, int out_size, void* d_ws, size_t ws_size,
                              hipStream_t stream)
{
  const float* x  = (const float*)d_in[0];
  const float* Wc = (const float*)d_in[1];
  const float* bc = (const float*)d_in[2];
  const float* Wg = (const float*)d_in[3];
  const float* Wu = (const float*)d_in[4];
  const float* Wd = (const float*)d_in[5];
  float* out = (float*)d_out;

  char* ws = (char*)d_ws;
  int*   counts = (int*)(ws + 0);              // 64 B
  int*   base   = (int*)(ws + 256);            // 36 B
  float* conf   = (float*)(ws + 1024);         // 128 KiB -> 132096
  int*   list   = (int*)(ws + 132096);         // 128 KiB -> 263168
  float* wlist  = (float*)(ws + 263168);       // 128 KiB -> 394240
  f16*   xh     = (f16*)(ws + 394240);         // 8 MiB   -> 8782848
  f16*   hbuf   = (f16*)(ws + 8782848);        // 32 MiB  -> 42337280
  f16*   W1     = (f16*)(ws + 42337280);       // 32 MiB  -> 75891712  (WgT, then WdT)
  f16*   W2     = (f16*)(ws + 75891712);       // 32 MiB  -> 109446144 (WuT)

  hipMemsetAsync(counts, 0, 64, stream);
  hipMemsetAsync(out, 0, (size_t)out_size * sizeof(float), stream);

  conf_kernel<<<T_TOK / 4, 256, 0, stream>>>(x, Wc, bc, conf);
  top2_kernel<<<T_TOK / 256, 256, 0, stream>>>(conf, counts, list, wlist);
  scan_kernel<<<1, 64, 0, stream>>>(counts, base);

  cvt_x_kernel<<<T_TOK * DDIM / 1024, 256, 0, stream>>>(x, xh);
  dim3 gt1(IDIM / 32, DDIM / 32, NE);
  tpose_kernel<<<gt1, 256, 0, stream>>>(Wg, W1, DDIM, IDIM);  // WgT [I][D]
  tpose_kernel<<<gt1, 256, 0, stream>>>(Wu, W2, DDIM, IDIM);  // WuT [I][D]

  dim3 g1(IDIM / 128, T_TOK / 128, NE);
  gemm1_kernel<<<g1, 256, 0, stream>>>(xh, W1, W2, counts, base, list, wlist, hbuf);

  dim3 gt2(DDIM / 32, IDIM / 32, NE);
  tpose_kernel<<<gt2, 256, 0, stream>>>(Wd, W1, IDIM, DDIM);  // WdT [D][I], reuse W1

  dim3 g2(DDIM / 128, T_TOK / 128, NE);
  gemm2_kernel<<<g2, 256, 0, stream>>>(hbuf, W1, counts, base, list, out);
}

// Round 4
// 457.621 us; speedup vs baseline: 1.0914x; 1.0237x over previous
//
#include <hip/hip_runtime.h>

#define T_TOK 4096
#define DDIM  1024
#define IDIM  2048
#define NE    8
#define TOTROWS 8192   // T_TOK * top_k

typedef unsigned short u16;
typedef unsigned int   u32;
typedef _Float16 f16;
typedef _Float16 f16x8 __attribute__((ext_vector_type(8)));
typedef _Float16 f16x4 __attribute__((ext_vector_type(4)));
typedef float    f32x4 __attribute__((ext_vector_type(4)));

// counted vmcnt wait: lets prefetched global_load_lds stay in flight (T4)
#define WAITV(N) asm volatile("s_waitcnt vmcnt(" #N ")" ::: "memory")

// async global->LDS, 16B per lane; LDS dest is wave-uniform base + lane*16
static __device__ __forceinline__ void gload16(const f16* g, f16* l) {
  __builtin_amdgcn_global_load_lds(
      (const __attribute__((address_space(1))) void*)g,
      (__attribute__((address_space(3))) void*)l, 16, 0, 0);
}

// ---- conf[t][e] = sigmoid(dot(x[t], Wc[e]) + bc[e]); one wave per token ----
__global__ __launch_bounds__(256) void conf_kernel(
    const float* __restrict__ x, const float* __restrict__ Wc,
    const float* __restrict__ bc, float* __restrict__ conf)
{
  int gid  = blockIdx.x * 256 + threadIdx.x;
  int t    = gid >> 6;
  int lane = threadIdx.x & 63;
  if (t >= T_TOK) return;
  const float* xr = x + (size_t)t * DDIM;
  float acc[NE];
#pragma unroll
  for (int e = 0; e < NE; e++) acc[e] = 0.f;
  for (int d = lane; d < DDIM; d += 64) {
    float xv = xr[d];
#pragma unroll
    for (int e = 0; e < NE; e++) acc[e] += xv * Wc[e * DDIM + d];
  }
#pragma unroll
  for (int off = 32; off > 0; off >>= 1) {
#pragma unroll
    for (int e = 0; e < NE; e++) acc[e] += __shfl_down(acc[e], off, 64);
  }
  if (lane == 0) {
#pragma unroll
    for (int e = 0; e < NE; e++)
      conf[t * NE + e] = 1.f / (1.f + expf(-(acc[e] + bc[e])));
  }
}

// ---- one thread per token: top-2 by conf (ties -> lower index), softmax ----
__global__ __launch_bounds__(256) void top2_kernel(
    const float* __restrict__ conf,
    int* __restrict__ counts, int* __restrict__ list, float* __restrict__ wlist)
{
  int t = blockIdx.x * 256 + threadIdx.x;
  if (t >= T_TOK) return;
  float c[NE];
#pragma unroll
  for (int e = 0; e < NE; e++) c[e] = conf[t * NE + e];
  int i0 = 0;
#pragma unroll
  for (int e = 1; e < NE; e++) if (c[e] > c[i0]) i0 = e;
  int i1 = (i0 == 0) ? 1 : 0;
#pragma unroll
  for (int e = 0; e < NE; e++) if (e != i0 && c[e] > c[i1]) i1 = e;
  float w1 = 1.f / (1.f + expf(c[i0] - c[i1]));
  float w0 = 1.f - w1;
  int s0 = atomicAdd(&counts[i0], 1);
  list[i0 * T_TOK + s0]  = t;
  wlist[i0 * T_TOK + s0] = w0;
  int s1 = atomicAdd(&counts[i1], 1);
  list[i1 * T_TOK + s1]  = t;
  wlist[i1 * T_TOK + s1] = w1;
}

// ---- prefix sum over 8 experts ---------------------------------------------
__global__ void scan_kernel(const int* __restrict__ counts, int* __restrict__ base)
{
  if (threadIdx.x == 0 && blockIdx.x == 0) {
    int s = 0;
    for (int e = 0; e < NE; e++) { base[e] = s; s += counts[e]; }
    base[NE] = s;
  }
}

// ---- x fp32 -> fp16 ---------------------------------------------------------
__global__ __launch_bounds__(256) void cvt_x_kernel(
    const float* __restrict__ x, f16* __restrict__ xh)
{
  int i = blockIdx.x * 256 + threadIdx.x;        // 1 float4 per thread
  float4 v = ((const float4*)x)[i];
  f16x4 h; h[0] = (f16)v.x; h[1] = (f16)v.y; h[2] = (f16)v.z; h[3] = (f16)v.w;
  ((f16x4*)xh)[i] = h;
}

// ---- transpose+convert: in [R][C] fp32 -> out [C][R] fp16 (per expert z) ---
__global__ __launch_bounds__(256) void tpose_kernel(
    const float* __restrict__ in, f16* __restrict__ out, int R, int C)
{
  __shared__ float t[32][33];
  const size_t mat = (size_t)R * C;
  const float* src = in  + (size_t)blockIdx.z * mat;
  f16*         dst = out + (size_t)blockIdx.z * mat;
  int c0 = blockIdx.x * 32, r0 = blockIdx.y * 32;
  int tx = threadIdx.x & 31, ty = threadIdx.x >> 5;   // 32 x 8
#pragma unroll
  for (int i = 0; i < 32; i += 8)
    t[ty + i][tx] = src[(size_t)(r0 + ty + i) * C + c0 + tx];
  __syncthreads();
#pragma unroll
  for (int i = 0; i < 32; i += 8)
    dst[(size_t)(c0 + ty + i) * R + r0 + tx] = (f16)t[tx][ty + i];
}

// fused Wg+Wu transpose: z = 0..15 -> (matrix m = z>>3, expert e = z&7)
__global__ __launch_bounds__(256) void tpose_gu_kernel(
    const float* __restrict__ Wg, const float* __restrict__ Wu,
    f16* __restrict__ W1, f16* __restrict__ W2)
{
  __shared__ float t[32][33];
  const int m = blockIdx.z >> 3, e = blockIdx.z & 7;
  const size_t mat = (size_t)DDIM * IDIM;
  const float* src = (m ? Wu : Wg) + (size_t)e * mat;
  f16*         dst = (m ? W2 : W1) + (size_t)e * mat;
  int c0 = blockIdx.x * 32, r0 = blockIdx.y * 32;
  int tx = threadIdx.x & 31, ty = threadIdx.x >> 5;
#pragma unroll
  for (int i = 0; i < 32; i += 8)
    t[ty + i][tx] = src[(size_t)(r0 + ty + i) * IDIM + c0 + tx];
  __syncthreads();
#pragma unroll
  for (int i = 0; i < 32; i += 8)
    dst[(size_t)(c0 + ty + i) * DDIM + r0 + tx] = (f16)t[tx][ty + i];
}

// ---- MFMA GEMM config -------------------------------------------------------
// 128x128 tile, BK=32, TRIPLE-buffered LDS, depth-2 counted-vmcnt pipeline,
// 4 waves (2x2), wave tile 64x64, mfma_f32_16x16x32_f16.
// LDS rows = 32 f16 = 64B = 4 slots of 16B. Swizzle (verified: 0 conflicts):
// phys_slot = kg ^ ((r15>>1)&3); inverse applied on per-lane GLOBAL source
// slot sl = (l&3) ^ ((l>>3)&3) since global_load_lds writes linearly.
//
// XCD-locality decode (T1): 1-D grid; e = bid&7 pins each expert to one XCD
// (consecutive blockIds round-robin across the 8 XCDs). y innermost so the
// 512 KiB weight strip for n0 + the ~2 MiB expert x-gather stay L2-resident
// across the y-sweep -> K-loop staging served from L2 (34.5 TB/s), not L3.
constexpr int BK = 32;

// ---- GEMM1: h[slot][n] = silu(x@Wg)*(x@Wu)*w, fp16 out ---------------------
__global__ __launch_bounds__(256, 2) void gemm1_kernel(
    const f16* __restrict__ xh, const f16* __restrict__ WgT, const f16* __restrict__ WuT,
    const int* __restrict__ counts, const int* __restrict__ base,
    const int* __restrict__ list, const float* __restrict__ wlist,
    f16* __restrict__ hbuf)
{
  const int bid   = blockIdx.x;
  const int e     = bid & 7;          // expert -> XCD pin
  const int inner = bid >> 3;         // 0..511
  const int n0    = (inner >> 5) * 128;   // 16 n-blocks, outer
  const int p0    = (inner & 31) * 128;   // 32 y-blocks, inner
  const int cnt   = counts[e];
  if (p0 >= cnt) return;

  __shared__ __align__(16) f16 As [3][128 * BK];
  __shared__ __align__(16) f16 Bgs[3][128 * BK];
  __shared__ __align__(16) f16 Bus[3][128 * BK];
  __shared__ int   tokS[128];
  __shared__ float wS[128];

  const int tid = threadIdx.x;
  if (tid < 128) {
    int p = p0 + tid;
    tokS[tid] = (p < cnt) ? list[e * T_TOK + p] : 0;
    wS[tid]   = (p < cnt) ? wlist[e * T_TOK + p] : 0.f;
  }
  __syncthreads();   // also drains tokS loads -> clean vmcnt accounting

  const int l   = tid & 63;
  const int w   = tid >> 6;
  const int wr  = w >> 1, wc = w & 1;
  const int r15 = l & 15;
  const int kg  = l >> 4;

  // staging source pointers (wave w stages row-groups j = 2w, 2w+1 of each tile)
  const int rl4 = l >> 2;                       // row within 16-row group
  const int sl  = (l & 3) ^ ((l >> 3) & 3);     // inverse-swizzled source slot
  const f16* WgE = WgT + ((size_t)e << 21);
  const f16* WuE = WuT + ((size_t)e << 21);
  const f16* srcA[2]; const f16* srcG[2]; const f16* srcU[2];
#pragma unroll
  for (int ii = 0; ii < 2; ii++) {
    int j = 2 * w + ii;
    int row = j * 16 + rl4;
    srcA[ii] = xh  + (size_t)tokS[row] * DDIM + sl * 8;
    srcG[ii] = WgE + (size_t)(n0 + row) * DDIM + sl * 8;
    srcU[ii] = WuE + (size_t)(n0 + row) * DDIM + sl * 8;
  }

  // fragment-read LDS offsets (f16 units)
  const int phys = kg ^ ((r15 >> 1) & 3);
  const int aoff = (wr * 64 + r15) * BK + phys * 8;   // + mi*512
  const int boff = (wc * 64 + r15) * BK + phys * 8;   // + ni*512

  f32x4 accg[4][4], accu[4][4];
#pragma unroll
  for (int a = 0; a < 4; a++)
#pragma unroll
    for (int bq = 0; bq < 4; bq++)
#pragma unroll
      for (int r = 0; r < 4; r++) { accg[a][bq][r] = 0.f; accu[a][bq][r] = 0.f; }

#define STAGE1(KT, B) do {                                   \
    int koff = (KT) * BK;                                    \
    _Pragma("unroll")                                        \
    for (int ii = 0; ii < 2; ii++) {                         \
      int j = 2 * w + ii;                                    \
      gload16(srcA[ii] + koff, &As [B][j * 512]);            \
      gload16(srcG[ii] + koff, &Bgs[B][j * 512]);            \
      gload16(srcU[ii] + koff, &Bus[B][j * 512]);            \
    }                                                        \
  } while (0)

  STAGE1(0, 0);          // 6 loads in flight
  STAGE1(1, 1);          // 12 in flight
  constexpr int NT = DDIM / BK;   // 32
  int cb = 0;            // compute buffer = kt % 3
  for (int kt = 0; kt < NT; kt++) {
    // wait for tile kt only; tile kt+1's 6 loads stay in flight (never drain 0)
    if (kt + 1 < NT) { WAITV(6); } else { WAITV(0); }
    __builtin_amdgcn_s_barrier();
    if (kt + 2 < NT) {
      int sb = (cb == 0) ? 2 : cb - 1;    // (kt+2)%3 — buffer freed by this barrier
      STAGE1(kt + 2, sb);                 // back to 12 in flight
    }

    f16x8 av[4], bgv[4], buv[4];
#pragma unroll
    for (int mi = 0; mi < 4; mi++) av[mi] = *(const f16x8*)&As[cb][aoff + mi * 512];
#pragma unroll
    for (int ni = 0; ni < 4; ni++) {
      bgv[ni] = *(const f16x8*)&Bgs[cb][boff + ni * 512];
      buv[ni] = *(const f16x8*)&Bus[cb][boff + ni * 512];
    }
    __builtin_amdgcn_s_setprio(1);
#pragma unroll
    for (int mi = 0; mi < 4; mi++)
#pragma unroll
      for (int ni = 0; ni < 4; ni++) {
        accg[mi][ni] = __builtin_amdgcn_mfma_f32_16x16x32_f16(av[mi], bgv[ni], accg[mi][ni], 0, 0, 0);
        accu[mi][ni] = __builtin_amdgcn_mfma_f32_16x16x32_f16(av[mi], buv[ni], accu[mi][ni], 0, 0, 0);
      }
    __builtin_amdgcn_s_setprio(0);
    cb = (cb == 2) ? 0 : cb + 1;
  }
#undef STAGE1

  // epilogue: 16x16 C/D layout: col=lane&15, row=(lane>>4)*4 + reg
  const int rowbase = base[e] + p0;
#pragma unroll
  for (int mi = 0; mi < 4; mi++)
#pragma unroll
    for (int ni = 0; ni < 4; ni++) {
      int col = n0 + wc * 64 + ni * 16 + r15;
#pragma unroll
      for (int r = 0; r < 4; r++) {
        int p = wr * 64 + mi * 16 + kg * 4 + r;
        if (p0 + p < cnt) {
          float g = accg[mi][ni][r], u = accu[mi][ni][r];
          hbuf[(size_t)(rowbase + p) * IDIM + col] = (f16)(g / (1.f + expf(-g)) * u * wS[p]);
        }
      }
    }
}

// ---- GEMM2: out[tok,:] += h_row @ Wd[e]  (fp32 atomic combine) -------------
__global__ __launch_bounds__(256, 3) void gemm2_kernel(
    const f16* __restrict__ hbuf, const f16* __restrict__ WdT,
    const int* __restrict__ counts, const int* __restrict__ base,
    const int* __restrict__ list, float* __restrict__ out)
{
  const int bid   = blockIdx.x;
  const int e     = bid & 7;          // expert -> XCD pin
  const int inner = bid >> 3;         // 0..255
  const int n0    = (inner >> 5) * 128;   // 8 n-blocks, outer
  const int p0    = (inner & 31) * 128;   // 32 y-blocks, inner
  const int cnt   = counts[e];
  if (p0 >= cnt) return;

  __shared__ __align__(16) f16 Hs [3][128 * BK];
  __shared__ __align__(16) f16 Bds[3][128 * BK];
  __shared__ int tokS[128];

  const int tid = threadIdx.x;
  if (tid < 128) {
    int p = p0 + tid;
    tokS[tid] = (p < cnt) ? list[e * T_TOK + p] : 0;
  }
  __syncthreads();

  const int l   = tid & 63;
  const int w   = tid >> 6;
  const int wr  = w >> 1, wc = w & 1;
  const int r15 = l & 15;
  const int kg  = l >> 4;

  const int rl4 = l >> 2;
  const int sl  = (l & 3) ^ ((l >> 3) & 3);
  const int rowbase = base[e] + p0;
  const f16* WdE = WdT + ((size_t)e << 21);
  const f16* srcH[2]; const f16* srcD[2];
#pragma unroll
  for (int ii = 0; ii < 2; ii++) {
    int j = 2 * w + ii;
    int row = j * 16 + rl4;
    int hr = rowbase + row; if (hr > TOTROWS - 1) hr = TOTROWS - 1;  // pad clamp
    srcH[ii] = hbuf + (size_t)hr * IDIM + sl * 8;
    srcD[ii] = WdE  + (size_t)(n0 + row) * IDIM + sl * 8;
  }

  const int phys = kg ^ ((r15 >> 1) & 3);
  const int aoff = (wr * 64 + r15) * BK + phys * 8;
  const int boff = (wc * 64 + r15) * BK + phys * 8;

  f32x4 acc[4][4];
#pragma unroll
  for (int a = 0; a < 4; a++)
#pragma unroll
    for (int bq = 0; bq < 4; bq++)
#pragma unroll
      for (int r = 0; r < 4; r++) acc[a][bq][r] = 0.f;

#define STAGE2(KT, B) do {                                   \
    int koff = (KT) * BK;                                    \
    _Pragma("unroll")                                        \
    for (int ii = 0; ii < 2; ii++) {                         \
      int j = 2 * w + ii;                                    \
      gload16(srcH[ii] + koff, &Hs [B][j * 512]);            \
      gload16(srcD[ii] + koff, &Bds[B][j * 512]);            \
    }                                                        \
  } while (0)

  STAGE2(0, 0);          // 4 in flight
  STAGE2(1, 1);          // 8 in flight
  constexpr int NT = IDIM / BK;   // 64
  int cb = 0;
  for (int kt = 0; kt < NT; kt++) {
    if (kt + 1 < NT) { WAITV(4); } else { WAITV(0); }
    __builtin_amdgcn_s_barrier();
    if (kt + 2 < NT) {
      int sb = (cb == 0) ? 2 : cb - 1;
      STAGE2(kt + 2, sb);
    }

    f16x8 av[4], bdv[4];
#pragma unroll
    for (int mi = 0; mi < 4; mi++) av[mi] = *(const f16x8*)&Hs[cb][aoff + mi * 512];
#pragma unroll
    for (int ni = 0; ni < 4; ni++) bdv[ni] = *(const f16x8*)&Bds[cb][boff + ni * 512];
    __builtin_amdgcn_s_setprio(1);
#pragma unroll
    for (int mi = 0; mi < 4; mi++)
#pragma unroll
      for (int ni = 0; ni < 4; ni++)
        acc[mi][ni] = __builtin_amdgcn_mfma_f32_16x16x32_f16(av[mi], bdv[ni], acc[mi][ni], 0, 0, 0);
    __builtin_amdgcn_s_setprio(0);
    cb = (cb == 2) ? 0 : cb + 1;
  }
#undef STAGE2

#pragma unroll
  for (int mi = 0; mi < 4; mi++)
#pragma unroll
    for (int ni = 0; ni < 4; ni++) {
      int col = n0 + wc * 64 + ni * 16 + r15;
#pragma unroll
      for (int r = 0; r < 4; r++) {
        int p = wr * 64 + mi * 16 + kg * 4 + r;
        if (p0 + p < cnt)
          atomicAdd(&out[(size_t)tokS[p] * DDIM + col], acc[mi][ni][r]);
      }
    }
}

// ---- launch -----------------------------------------------------------------
extern "C" void kernel_launch(void* const* d_in, const int* in_sizes, int n_in,
                              void* d_out, int out_size, void* d_ws, size_t ws_size,
                              hipStream_t stream)
{
  const float* x  = (const float*)d_in[0];
  const float* Wc = (const float*)d_in[1];
  const float* bc = (const float*)d_in[2];
  const float* Wg = (const float*)d_in[3];
  const float* Wu = (const float*)d_in[4];
  const float* Wd = (const float*)d_in[5];
  float* out = (float*)d_out;

  char* ws = (char*)d_ws;
  int*   counts = (int*)(ws + 0);              // 64 B
  int*   base   = (int*)(ws + 256);            // 36 B
  float* conf   = (float*)(ws + 1024);         // 128 KiB -> 132096
  int*   list   = (int*)(ws + 132096);         // 128 KiB -> 263168
  float* wlist  = (float*)(ws + 263168);       // 128 KiB -> 394240
  f16*   xh     = (f16*)(ws + 394240);         // 8 MiB   -> 8782848
  f16*   hbuf   = (f16*)(ws + 8782848);        // 32 MiB  -> 42337280
  f16*   W1     = (f16*)(ws + 42337280);       // 32 MiB  -> 75891712  (WgT, then WdT)
  f16*   W2     = (f16*)(ws + 75891712);       // 32 MiB  -> 109446144 (WuT)

  hipMemsetAsync(counts, 0, 64, stream);
  hipMemsetAsync(out, 0, (size_t)out_size * sizeof(float), stream);

  conf_kernel<<<T_TOK / 4, 256, 0, stream>>>(x, Wc, bc, conf);
  top2_kernel<<<T_TOK / 256, 256, 0, stream>>>(conf, counts, list, wlist);
  scan_kernel<<<1, 64, 0, stream>>>(counts, base);

  cvt_x_kernel<<<T_TOK * DDIM / 1024, 256, 0, stream>>>(x, xh);
  dim3 gtgu(IDIM / 32, DDIM / 32, 2 * NE);
  tpose_gu_kernel<<<gtgu, 256, 0, stream>>>(Wg, Wu, W1, W2);  // WgT->W1, WuT->W2

  gemm1_kernel<<<16 * 32 * NE, 256, 0, stream>>>(xh, W1, W2, counts, base, list, wlist, hbuf);

  dim3 gt2(DDIM / 32, IDIM / 32, NE);
  tpose_kernel<<<gt2, 256, 0, stream>>>(Wd, W1, IDIM, DDIM);  // WdT [D][I], reuse W1

  gemm2_kernel<<<8 * 32 * NE, 256, 0, stream>>>(hbuf, W1, counts, base, list, out);
}